// Round 9
// baseline (331.571 us; speedup 1.0000x reference)
//
#include <hip/hip_runtime.h>
#include <hip/hip_bf16.h>

// B=4, T=2048, D=1024, H=16, DK=DV=64
#define TT 2048

typedef __attribute__((ext_vector_type(8))) short bf16x8;
typedef __attribute__((ext_vector_type(4))) short s16x4;
typedef __attribute__((ext_vector_type(4))) float f32x4;
typedef __attribute__((ext_vector_type(16))) float f32x16;
typedef __attribute__((ext_vector_type(4))) unsigned int u32x4;

__device__ __forceinline__ unsigned short f2bf(float x) {
    unsigned u = __float_as_uint(x);
    return (unsigned short)((u + 0x7fffu + ((u >> 16) & 1u)) >> 16);
}

typedef __attribute__((address_space(1))) const unsigned int g_u32;
typedef __attribute__((address_space(3))) unsigned int l_u32;
__device__ __forceinline__ void gll16(const void* g, void* l) {
    __builtin_amdgcn_global_load_lds((g_u32*)g, (l_u32*)l, 16, 0, 0);
}

// scale/sqrt(dk) * log2(e), folded into Q so attention P = exp2(e) directly
#define QSCALE 0.1803368801111244f

// ---------------------------------------------------------------------------
// fp32 -> bf16 convert; grid.y selects (src,dst) pair
// ---------------------------------------------------------------------------
__global__ __launch_bounds__(256) void conv_x2_kernel(
    const float* __restrict__ s0, short* __restrict__ d0,
    const float* __restrict__ s1, short* __restrict__ d1, int n8) {
    const int i = blockIdx.x * 256 + threadIdx.x;
    if (i >= n8) return;
    const float* src = blockIdx.y ? s1 : s0;
    short* dst = blockIdx.y ? d1 : d0;
    const float4 a = ((const float4*)src)[2 * i];
    const float4 b = ((const float4*)src)[2 * i + 1];
    bf16x8 o;
    o[0] = (short)f2bf(a.x); o[1] = (short)f2bf(a.y);
    o[2] = (short)f2bf(a.z); o[3] = (short)f2bf(a.w);
    o[4] = (short)f2bf(b.x); o[5] = (short)f2bf(b.y);
    o[6] = (short)f2bf(b.z); o[7] = (short)f2bf(b.w);
    ((bf16x8*)dst)[i] = o;
}

// ---------------------------------------------------------------------------
// Weight transpose+convert, all four weights in one launch (grid.z = 0..3)
// ---------------------------------------------------------------------------
__global__ __launch_bounds__(256) void conv_w_all(
    const float* __restrict__ W0, const float* __restrict__ W1,
    const float* __restrict__ W2, const float* __restrict__ W3,
    short* __restrict__ Wt) {
    __shared__ short t[64][72];
    const int z = blockIdx.z;
    const float* W = (z == 0) ? W0 : (z == 1) ? W1 : (z == 2) ? W2 : W3;
    short* dst = Wt + (size_t)z * 1024 * 1024;
    const int bx = blockIdx.x;
    const int by = blockIdx.y;
    const int tid = threadIdx.x;
    const int d0 = by * 64;
    {
        const int r = tid >> 2;
        const int c0 = (tid & 3) * 16;
        const float* srow = (z < 3)
                                ? (W + (size_t)bx * 65536 + (size_t)(d0 + r) * 64 + c0)
                                : (W + (size_t)(d0 + r) * 1024 + bx * 64 + c0);
#pragma unroll
        for (int q = 0; q < 4; ++q) {
            const float4 v = *(const float4*)(srow + q * 4);
            t[r][c0 + q * 4 + 0] = (short)f2bf(v.x);
            t[r][c0 + q * 4 + 1] = (short)f2bf(v.y);
            t[r][c0 + q * 4 + 2] = (short)f2bf(v.z);
            t[r][c0 + q * 4 + 3] = (short)f2bf(v.w);
        }
    }
    __syncthreads();
    {
        const int j = tid >> 2;
        const int c0 = (tid & 3) * 16;
        bf16x8 v0, v1;
#pragma unroll
        for (int q = 0; q < 8; ++q) v0[q] = t[c0 + q][j];
#pragma unroll
        for (int q = 0; q < 8; ++q) v1[q] = t[c0 + 8 + q][j];
        short* drow = dst + (size_t)(bx * 64 + j) * 1024 + d0 + c0;
        *(bf16x8*)drow = v0;
        *(bf16x8*)(drow + 8) = v1;
    }
}

// ---------------------------------------------------------------------------
// Shared GEMM main loop (128x128x64, 4 waves): computes acc for tile (m0,n0).
// ---------------------------------------------------------------------------
__device__ __forceinline__ void gemm_core(const short* __restrict__ A,
                                          const short* __restrict__ Bt,
                                          int m0, int n0, int tid,
                                          short* As, short* Bs, f32x4 acc[4][4]) {
    const int w = tid >> 6, lane = tid & 63;
    const int l16 = lane & 15, lk = lane >> 4;
    const int wr = w >> 1, wc = w & 1;
    const int srow = lane >> 3;
    const int schk = lane & 7;
#pragma unroll
    for (int i = 0; i < 4; ++i)
#pragma unroll
        for (int j = 0; j < 4; ++j)
#pragma unroll
            for (int r = 0; r < 4; ++r) acc[i][j][r] = 0.f;

    for (int k0 = 0; k0 < 1024; k0 += 64) {
#pragma unroll
        for (int p = 0; p < 4; ++p) {
            const int row = p * 32 + w * 8 + srow;
            const int ca = schk ^ (row & 7);
            gll16(A + (size_t)(m0 + row) * 1024 + k0 + ca * 8, &As[p * 2048 + w * 512]);
            gll16(Bt + (size_t)(n0 + row) * 1024 + k0 + ca * 8, &Bs[p * 2048 + w * 512]);
        }
        __syncthreads();
#pragma unroll
        for (int kc = 0; kc < 2; ++kc) {
            bf16x8 a[4], b[4];
#pragma unroll
            for (int mi = 0; mi < 4; ++mi) {
                const int row = wr * 64 + mi * 16 + l16;
                a[mi] = *(const bf16x8*)&As[row * 64 + (((kc * 4 + lk) ^ (row & 7)) * 8)];
            }
#pragma unroll
            for (int ni = 0; ni < 4; ++ni) {
                const int row = wc * 64 + ni * 16 + l16;
                b[ni] = *(const bf16x8*)&Bs[row * 64 + (((kc * 4 + lk) ^ (row & 7)) * 8)];
            }
#pragma unroll
            for (int mi = 0; mi < 4; ++mi)
#pragma unroll
                for (int ni = 0; ni < 4; ++ni)
                    acc[mi][ni] = __builtin_amdgcn_mfma_f32_16x16x32_bf16(
                        a[mi], b[ni], acc[mi][ni], 0, 0, 0);
        }
        __syncthreads();
    }
}

// ---------------------------------------------------------------------------
// Q and K projections fused in one launch (grid.z = 0:Q, 1:K)
// ---------------------------------------------------------------------------
__global__ __launch_bounds__(256) void gemm_qk_kernel(
    const short* __restrict__ Xq, const short* __restrict__ Xk,
    const short* __restrict__ Wt, const float* __restrict__ bq,
    const float* __restrict__ bk, short* __restrict__ Qp,
    short* __restrict__ Kp) {
    __shared__ short As[8192];
    __shared__ short Bs[8192];
    const int z = blockIdx.z;
    const short* A = z ? Xk : Xq;
    const short* Bt = Wt + (size_t)z * 1024 * 1024;
    const float* bias = z ? bk : bq;
    short* outb = z ? Kp : Qp;
    const int id = blockIdx.x;
    const int swz = (id & 7) * 64 + (id >> 3);
    const int n0 = (swz & 7) * 128;
    const int m0 = (swz >> 3) * 128;
    const int tid = threadIdx.x;
    const int w = tid >> 6, lane = tid & 63;
    const int l16 = lane & 15, lk = lane >> 4;
    const int wr = w >> 1, wc = w & 1;

    f32x4 acc[4][4];
    gemm_core(A, Bt, m0, n0, tid, As, Bs, acc);

#pragma unroll
    for (int mi = 0; mi < 4; ++mi) {
        const int gm0 = m0 + wr * 64 + mi * 16 + lk * 4;
#pragma unroll
        for (int ni = 0; ni < 4; ++ni) {
            const int gn = n0 + wc * 64 + ni * 16 + l16;
            const float bv = bias[gn];
            if (z == 0) {
                const float bvs = bv * QSCALE;
#pragma unroll
                for (int r = 0; r < 4; ++r) {
                    const int gm = gm0 + r;
                    outb[((size_t)((gm >> 11) * 16 + (gn >> 6)) * 2048 + (gm & 2047)) * 64 +
                         (gn & 63)] = (short)f2bf(fmaf(acc[mi][ni][r], QSCALE, bvs));
                }
            } else {
#pragma unroll
                for (int r = 0; r < 4; ++r) {
                    const int gm = gm0 + r;
                    const int t = gm & 2047;
                    const int j = gn & 63;
                    const int jsw = (((j >> 3) ^ (t & 7)) << 3) | (j & 7);
                    outb[((size_t)((gm >> 11) * 16 + (gn >> 6)) * 2048 + t) * 64 + jsw] =
                        (short)f2bf(acc[mi][ni][r] + bv);
                }
            }
        }
    }
}

// ---------------------------------------------------------------------------
// MODE 1: V^T bf16 out [b,h,j,t] chunk-swizzled t^(j&7);  MODE 2: fp32 final
// ---------------------------------------------------------------------------
template <int MODE>
__global__ __launch_bounds__(256) void gemm_kernel(
    const short* __restrict__ A, const short* __restrict__ Bt,
    const float* __restrict__ bias, short* __restrict__ outb,
    float* __restrict__ outf) {
    __shared__ short As[8192];
    __shared__ short Bs[8192];
    const int id = blockIdx.x;
    const int swz = (id & 7) * 64 + (id >> 3);
    const int n0 = (swz & 7) * 128;
    const int m0 = (swz >> 3) * 128;
    const int tid = threadIdx.x;
    const int w = tid >> 6, lane = tid & 63;
    const int l16 = lane & 15, lk = lane >> 4;
    const int wr = w >> 1, wc = w & 1;

    f32x4 acc[4][4];
    gemm_core(A, Bt, m0, n0, tid, As, Bs, acc);

#pragma unroll
    for (int mi = 0; mi < 4; ++mi) {
        const int gm0 = m0 + wr * 64 + mi * 16 + lk * 4;
#pragma unroll
        for (int ni = 0; ni < 4; ++ni) {
            const int gn = n0 + wc * 64 + ni * 16 + l16;
            const float bv = bias[gn];
            if (MODE == 2) {
#pragma unroll
                for (int r = 0; r < 4; ++r)
                    outf[(size_t)(gm0 + r) * 1024 + gn] = acc[mi][ni][r] + bv;
            } else {  // MODE 1
                s16x4 pk;
#pragma unroll
                for (int r = 0; r < 4; ++r) pk[r] = (short)f2bf(acc[mi][ni][r] + bv);
                const int t0 = gm0 & 2047;
                const int j = gn & 63;
                const int tsw = (t0 & ~63) | ((((t0 >> 3) & 7) ^ (j & 7)) << 3) | (t0 & 7);
                *(s16x4*)&outb[(((size_t)((gm0 >> 11) * 16 + (gn >> 6))) * 64 + j) * 2048 +
                               tsw] = pk;
            }
        }
    }
}

// ---------------------------------------------------------------------------
// Flash attention, 32x32x16 MFMA, in-register softmax, s-split wave pairs.
// 8 waves = 4 q-groups x 2 s-parities; partials combine additively via a
// union-overlaid LDS scratch (layout guaranteed). exp2f (NOT inline asm:
// trans-op hazard needs compiler-inserted wait states — R8 lesson).
// ---------------------------------------------------------------------------
__global__ __launch_bounds__(512, 6) void attn_kernel(
    const short* __restrict__ Qp, const short* __restrict__ Kp,
    const short* __restrict__ VTp, short* __restrict__ heads) {
    __shared__ union SMem {
        struct {
            short Ks[2][4096];   // [parity][64x64 tile], chunk-swizzled
            short VTs[2][4096];
        } t;
        float accF[8192];        // epilogue pair-combine scratch (32 KB)
    } sm;
    __shared__ float tsx[256];
    const int tid = threadIdx.x;
    const int w = tid >> 6, lane = tid & 63;
    const int l31 = lane & 31, hi = lane >> 5;
    const int g = w >> 1, par = w & 1;
    const int id = blockIdx.x;
    const int swz = (id & 7) * 128 + (id >> 3);  // 1024 blocks, XCD-contiguous
    const int qbase = (swz & 15) * 128;
    const int bh = swz >> 4;
    const size_t kvbase = (size_t)bh * TT * 64;

    // Q B-fragments: col q = l31, k(d) = sl*16 + hi*8 + j
    bf16x8 qf[4];
    {
        const short* Qw = Qp + kvbase + (size_t)(qbase + g * 32 + l31) * 64 + hi * 8;
#pragma unroll
        for (int sl = 0; sl < 4; ++sl) qf[sl] = *(const bf16x8*)(Qw + sl * 16);
    }

    f32x16 acc[2];
#pragma unroll
    for (int vb = 0; vb < 2; ++vb)
#pragma unroll
        for (int r = 0; r < 16; ++r) acc[vb][r] = 0.f;
    float ts_acc = 0.f;

    // staging: 4 gll16/thread covers 2 K-tiles + 2 V-tiles (even+odd parity)
    const int strow = w * 8 + (lane >> 3);
    const int sca = lane & 7;  // sources pre-swizzled in global -> linear copy

    for (int it = 0; it < 16; ++it) {
        const int s0 = it * 128;
        gll16(Kp + kvbase + (size_t)(s0 + strow) * 64 + sca * 8, &sm.t.Ks[0][w * 512]);
        gll16(Kp + kvbase + (size_t)(s0 + 64 + strow) * 64 + sca * 8,
              &sm.t.Ks[1][w * 512]);
        gll16(VTp + kvbase + (size_t)strow * 2048 + s0 + sca * 8, &sm.t.VTs[0][w * 512]);
        gll16(VTp + kvbase + (size_t)strow * 2048 + s0 + 64 + sca * 8,
              &sm.t.VTs[1][w * 512]);
        __syncthreads();

        u32x4 pa[4];  // PV A-frags
#pragma unroll
        for (int sb = 0; sb < 2; ++sb) {
            f32x16 e;
#pragma unroll
            for (int r = 0; r < 16; ++r) e[r] = 0.f;
            __builtin_amdgcn_s_setprio(1);
#pragma unroll
            for (int sl = 0; sl < 4; ++sl) {
                const int row = sb * 32 + l31;
                const bf16x8 kf = *(const bf16x8*)&sm.t.Ks[par][row * 64 +
                                                        (((sl * 2 + hi) ^ (row & 7)) * 8)];
                e = __builtin_amdgcn_mfma_f32_32x32x16_bf16(kf, qf[sl], e, 0, 0, 0);
            }
            __builtin_amdgcn_s_setprio(0);
            float p[16];
#pragma unroll
            for (int r = 0; r < 16; ++r) p[r] = exp2f(e[r]);
#pragma unroll
            for (int r = 0; r < 16; r += 4)
                ts_acc += ((p[r] + p[r + 1]) + (p[r + 2] + p[r + 3]));
            unsigned u[4][2];
#pragma unroll
            for (int A = 0; A < 4; ++A)
#pragma unroll
                for (int b = 0; b < 2; ++b)
                    asm("v_cvt_pk_bf16_f32 %0, %1, %2"
                        : "=v"(u[A][b])
                        : "v"(p[4 * A + 2 * b]), "v"(p[4 * A + 2 * b + 1]));
#pragma unroll
            for (int k1 = 0; k1 < 2; ++k1) {
#pragma unroll
                for (int b = 0; b < 2; ++b) {
                    unsigned p0 = u[2 * k1][b], p1 = u[2 * k1 + 1][b];
                    asm("v_permlane32_swap_b32 %0, %1" : "+v"(p0), "+v"(p1));
                    pa[sb * 2 + k1][b] = p0;
                    pa[sb * 2 + k1][2 + b] = p1;
                }
            }
        }
        __builtin_amdgcn_s_setprio(1);
#pragma unroll
        for (int vb = 0; vb < 2; ++vb) {
#pragma unroll
            for (int ks = 0; ks < 4; ++ks) {
                const int row = vb * 32 + l31;
                const bf16x8 vf = *(const bf16x8*)&sm.t.VTs[par][row * 64 +
                                                        (((ks * 2 + hi) ^ (row & 7)) * 8)];
                const bf16x8 paf = __builtin_bit_cast(bf16x8, pa[ks]);
                acc[vb] = __builtin_amdgcn_mfma_f32_32x32x16_bf16(paf, vf, acc[vb],
                                                                  0, 0, 0);
            }
        }
        __builtin_amdgcn_s_setprio(0);
        __syncthreads();
    }

    // pair-combine: odd-parity wave dumps partials to LDS; even adds them
    if (par == 1) {
#pragma unroll
        for (int vb = 0; vb < 2; ++vb)
#pragma unroll
            for (int r = 0; r < 16; ++r)
                sm.accF[g * 2048 + (vb * 16 + r) * 64 + lane] = acc[vb][r];
        tsx[g * 64 + lane] = ts_acc;
    }
    __syncthreads();
    if (par == 0) {
#pragma unroll
        for (int vb = 0; vb < 2; ++vb)
#pragma unroll
            for (int r = 0; r < 16; ++r)
                acc[vb][r] += sm.accF[g * 2048 + (vb * 16 + r) * 64 + lane];
        ts_acc += tsx[g * 64 + lane];

        float l = ts_acc;
        l += __shfl_xor(l, 32);
        const float linv = 1.0f / l;
        const int b_ = bh >> 4, h = bh & 15;
#pragma unroll
        for (int r = 0; r < 16; ++r) {
            const int qrow = (r & 3) + 8 * (r >> 2) + 4 * hi;
            const float inv = __shfl(linv, qrow);
            const int qg = qbase + g * 32 + qrow;
            const size_t base = ((size_t)(b_ * TT + qg)) * 1024 + h * 64 + l31;
            heads[base] = (short)f2bf(acc[0][r] * inv);
            heads[base + 32] = (short)f2bf(acc[1][r] * inv);
        }
    }
}

extern "C" void kernel_launch(void* const* d_in, const int* in_sizes, int n_in,
                              void* d_out, int out_size, void* d_ws, size_t ws_size,
                              hipStream_t stream) {
    const float* q = (const float*)d_in[0];
    const float* k = (const float*)d_in[1];
    const float* v = (const float*)d_in[2];
    const float* Wq = (const float*)d_in[3];
    const float* bq = (const float*)d_in[4];
    const float* Wk = (const float*)d_in[5];
    const float* bk = (const float*)d_in[6];
    const float* Wv = (const float*)d_in[7];
    const float* bv = (const float*)d_in[8];
    const float* Wo = (const float*)d_in[9];
    const float* bo = (const float*)d_in[10];
    float* out = (float*)d_out;

    const size_t SEG = (size_t)4 * 16 * 2048 * 64;  // 8,388,608 bf16 elems
    short* Qp = (short*)d_out;  // d_out doubles as Q/K scratch until final GEMM
    short* Kp = Qp + SEG;
    // ws: Xq | Xk (reused v->VT-input) | Wt x4 | VTp  (= 58.8 MB)
    short* ws = (short*)d_ws;
    short* Xq = ws;                  // later reused for heads
    short* Xk = Xq + SEG;
    short* Wt = Xk + SEG;
    short* VTp = Wt + (size_t)4 * 1024 * 1024;

    dim3 blk(256);
    const int n8 = (int)(SEG / 8);
    dim3 gcv2((n8 + 255) / 256, 2);
    dim3 gcv((n8 + 255) / 256);
    dim3 gwa(16, 16, 4);
    const size_t WSEG = (size_t)1024 * 1024;

    conv_w_all<<<gwa, blk, 0, stream>>>(Wq, Wk, Wv, Wo, Wt);
    conv_x2_kernel<<<gcv2, blk, 0, stream>>>(q, Xq, k, Xk, n8);
    gemm_qk_kernel<<<dim3(512, 1, 2), blk, 0, stream>>>(Xq, Xk, Wt, bq, bk, Qp, Kp);
    conv_x2_kernel<<<gcv, blk, 0, stream>>>(v, Xk, v, Xk, n8);  // v -> Xk (reuse)
    gemm_kernel<1><<<dim3(512), blk, 0, stream>>>(Xk, Wt + 2 * WSEG, bv, VTp, nullptr);
    attn_kernel<<<dim3(1024), dim3(512), 0, stream>>>(Qp, Kp, VTp, Xq /*heads*/);
    gemm_kernel<2><<<dim3(512), blk, 0, stream>>>(Xq, Wt + 3 * WSEG, bo, nullptr, out);
}

// Round 10
// 264.606 us; speedup vs baseline: 1.2531x; 1.2531x over previous
//
#include <hip/hip_runtime.h>
#include <hip/hip_bf16.h>

// B=4, T=2048, D=1024, H=16, DK=DV=64
#define TT 2048

typedef __attribute__((ext_vector_type(8))) short bf16x8;
typedef __attribute__((ext_vector_type(4))) short s16x4;
typedef __attribute__((ext_vector_type(4))) float f32x4;
typedef __attribute__((ext_vector_type(16))) float f32x16;
typedef __attribute__((ext_vector_type(4))) unsigned int u32x4;

__device__ __forceinline__ unsigned short f2bf(float x) {
    unsigned u = __float_as_uint(x);
    return (unsigned short)((u + 0x7fffu + ((u >> 16) & 1u)) >> 16);
}

typedef __attribute__((address_space(1))) const unsigned int g_u32;
typedef __attribute__((address_space(3))) unsigned int l_u32;
__device__ __forceinline__ void gll16(const void* g, void* l) {
    __builtin_amdgcn_global_load_lds((g_u32*)g, (l_u32*)l, 16, 0, 0);
}

// scale/sqrt(dk) * log2(e), folded into Q so attention P = exp2(e) directly
#define QSCALE 0.1803368801111244f

// ---------------------------------------------------------------------------
// fp32 -> bf16 convert; grid.y selects (src,dst) pair
// ---------------------------------------------------------------------------
__global__ __launch_bounds__(256) void conv_x2_kernel(
    const float* __restrict__ s0, short* __restrict__ d0,
    const float* __restrict__ s1, short* __restrict__ d1, int n8) {
    const int i = blockIdx.x * 256 + threadIdx.x;
    if (i >= n8) return;
    const float* src = blockIdx.y ? s1 : s0;
    short* dst = blockIdx.y ? d1 : d0;
    const float4 a = ((const float4*)src)[2 * i];
    const float4 b = ((const float4*)src)[2 * i + 1];
    bf16x8 o;
    o[0] = (short)f2bf(a.x); o[1] = (short)f2bf(a.y);
    o[2] = (short)f2bf(a.z); o[3] = (short)f2bf(a.w);
    o[4] = (short)f2bf(b.x); o[5] = (short)f2bf(b.y);
    o[6] = (short)f2bf(b.z); o[7] = (short)f2bf(b.w);
    ((bf16x8*)dst)[i] = o;
}

// ---------------------------------------------------------------------------
// Weight transpose+convert, all four weights in one launch (grid.z = 0..3)
// ---------------------------------------------------------------------------
__global__ __launch_bounds__(256) void conv_w_all(
    const float* __restrict__ W0, const float* __restrict__ W1,
    const float* __restrict__ W2, const float* __restrict__ W3,
    short* __restrict__ Wt) {
    __shared__ short t[64][72];
    const int z = blockIdx.z;
    const float* W = (z == 0) ? W0 : (z == 1) ? W1 : (z == 2) ? W2 : W3;
    short* dst = Wt + (size_t)z * 1024 * 1024;
    const int bx = blockIdx.x;
    const int by = blockIdx.y;
    const int tid = threadIdx.x;
    const int d0 = by * 64;
    {
        const int r = tid >> 2;
        const int c0 = (tid & 3) * 16;
        const float* srow = (z < 3)
                                ? (W + (size_t)bx * 65536 + (size_t)(d0 + r) * 64 + c0)
                                : (W + (size_t)(d0 + r) * 1024 + bx * 64 + c0);
#pragma unroll
        for (int q = 0; q < 4; ++q) {
            const float4 v = *(const float4*)(srow + q * 4);
            t[r][c0 + q * 4 + 0] = (short)f2bf(v.x);
            t[r][c0 + q * 4 + 1] = (short)f2bf(v.y);
            t[r][c0 + q * 4 + 2] = (short)f2bf(v.z);
            t[r][c0 + q * 4 + 3] = (short)f2bf(v.w);
        }
    }
    __syncthreads();
    {
        const int j = tid >> 2;
        const int c0 = (tid & 3) * 16;
        bf16x8 v0, v1;
#pragma unroll
        for (int q = 0; q < 8; ++q) v0[q] = t[c0 + q][j];
#pragma unroll
        for (int q = 0; q < 8; ++q) v1[q] = t[c0 + 8 + q][j];
        short* drow = dst + (size_t)(bx * 64 + j) * 1024 + d0 + c0;
        *(bf16x8*)drow = v0;
        *(bf16x8*)(drow + 8) = v1;
    }
}

// ---------------------------------------------------------------------------
// Shared GEMM main loop (128x128x64, 4 waves): computes acc for tile (m0,n0).
// ---------------------------------------------------------------------------
__device__ __forceinline__ void gemm_core(const short* __restrict__ A,
                                          const short* __restrict__ Bt,
                                          int m0, int n0, int tid,
                                          short* As, short* Bs, f32x4 acc[4][4]) {
    const int w = tid >> 6, lane = tid & 63;
    const int l16 = lane & 15, lk = lane >> 4;
    const int wr = w >> 1, wc = w & 1;
    const int srow = lane >> 3;
    const int schk = lane & 7;
#pragma unroll
    for (int i = 0; i < 4; ++i)
#pragma unroll
        for (int j = 0; j < 4; ++j)
#pragma unroll
            for (int r = 0; r < 4; ++r) acc[i][j][r] = 0.f;

    for (int k0 = 0; k0 < 1024; k0 += 64) {
#pragma unroll
        for (int p = 0; p < 4; ++p) {
            const int row = p * 32 + w * 8 + srow;
            const int ca = schk ^ (row & 7);
            gll16(A + (size_t)(m0 + row) * 1024 + k0 + ca * 8, &As[p * 2048 + w * 512]);
            gll16(Bt + (size_t)(n0 + row) * 1024 + k0 + ca * 8, &Bs[p * 2048 + w * 512]);
        }
        __syncthreads();
#pragma unroll
        for (int kc = 0; kc < 2; ++kc) {
            bf16x8 a[4], b[4];
#pragma unroll
            for (int mi = 0; mi < 4; ++mi) {
                const int row = wr * 64 + mi * 16 + l16;
                a[mi] = *(const bf16x8*)&As[row * 64 + (((kc * 4 + lk) ^ (row & 7)) * 8)];
            }
#pragma unroll
            for (int ni = 0; ni < 4; ++ni) {
                const int row = wc * 64 + ni * 16 + l16;
                b[ni] = *(const bf16x8*)&Bs[row * 64 + (((kc * 4 + lk) ^ (row & 7)) * 8)];
            }
#pragma unroll
            for (int mi = 0; mi < 4; ++mi)
#pragma unroll
                for (int ni = 0; ni < 4; ++ni)
                    acc[mi][ni] = __builtin_amdgcn_mfma_f32_16x16x32_bf16(
                        a[mi], b[ni], acc[mi][ni], 0, 0, 0);
        }
        __syncthreads();
    }
}

// ---------------------------------------------------------------------------
// Q and K projections fused in one launch (grid.z = 0:Q, 1:K)
// ---------------------------------------------------------------------------
__global__ __launch_bounds__(256) void gemm_qk_kernel(
    const short* __restrict__ Xq, const short* __restrict__ Xk,
    const short* __restrict__ Wt, const float* __restrict__ bq,
    const float* __restrict__ bk, short* __restrict__ Qp,
    short* __restrict__ Kp) {
    __shared__ short As[8192];
    __shared__ short Bs[8192];
    const int z = blockIdx.z;
    const short* A = z ? Xk : Xq;
    const short* Bt = Wt + (size_t)z * 1024 * 1024;
    const float* bias = z ? bk : bq;
    short* outb = z ? Kp : Qp;
    const int id = blockIdx.x;
    const int swz = (id & 7) * 64 + (id >> 3);
    const int n0 = (swz & 7) * 128;
    const int m0 = (swz >> 3) * 128;
    const int tid = threadIdx.x;
    const int w = tid >> 6, lane = tid & 63;
    const int l16 = lane & 15, lk = lane >> 4;
    const int wr = w >> 1, wc = w & 1;

    f32x4 acc[4][4];
    gemm_core(A, Bt, m0, n0, tid, As, Bs, acc);

#pragma unroll
    for (int mi = 0; mi < 4; ++mi) {
        const int gm0 = m0 + wr * 64 + mi * 16 + lk * 4;
#pragma unroll
        for (int ni = 0; ni < 4; ++ni) {
            const int gn = n0 + wc * 64 + ni * 16 + l16;
            const float bv = bias[gn];
            if (z == 0) {
                const float bvs = bv * QSCALE;
#pragma unroll
                for (int r = 0; r < 4; ++r) {
                    const int gm = gm0 + r;
                    outb[((size_t)((gm >> 11) * 16 + (gn >> 6)) * 2048 + (gm & 2047)) * 64 +
                         (gn & 63)] = (short)f2bf(fmaf(acc[mi][ni][r], QSCALE, bvs));
                }
            } else {
#pragma unroll
                for (int r = 0; r < 4; ++r) {
                    const int gm = gm0 + r;
                    const int t = gm & 2047;
                    const int j = gn & 63;
                    const int jsw = (((j >> 3) ^ (t & 7)) << 3) | (j & 7);
                    outb[((size_t)((gm >> 11) * 16 + (gn >> 6)) * 2048 + t) * 64 + jsw] =
                        (short)f2bf(acc[mi][ni][r] + bv);
                }
            }
        }
    }
}

// ---------------------------------------------------------------------------
// MODE 1: V^T bf16 out [b,h,j,t] chunk-swizzled t^(j&7);  MODE 2: fp32 final
// ---------------------------------------------------------------------------
template <int MODE>
__global__ __launch_bounds__(256) void gemm_kernel(
    const short* __restrict__ A, const short* __restrict__ Bt,
    const float* __restrict__ bias, short* __restrict__ outb,
    float* __restrict__ outf) {
    __shared__ short As[8192];
    __shared__ short Bs[8192];
    const int id = blockIdx.x;
    const int swz = (id & 7) * 64 + (id >> 3);
    const int n0 = (swz & 7) * 128;
    const int m0 = (swz >> 3) * 128;
    const int tid = threadIdx.x;
    const int w = tid >> 6, lane = tid & 63;
    const int l16 = lane & 15, lk = lane >> 4;
    const int wr = w >> 1, wc = w & 1;

    f32x4 acc[4][4];
    gemm_core(A, Bt, m0, n0, tid, As, Bs, acc);

#pragma unroll
    for (int mi = 0; mi < 4; ++mi) {
        const int gm0 = m0 + wr * 64 + mi * 16 + lk * 4;
#pragma unroll
        for (int ni = 0; ni < 4; ++ni) {
            const int gn = n0 + wc * 64 + ni * 16 + l16;
            const float bv = bias[gn];
            if (MODE == 2) {
#pragma unroll
                for (int r = 0; r < 4; ++r)
                    outf[(size_t)(gm0 + r) * 1024 + gn] = acc[mi][ni][r] + bv;
            } else {  // MODE 1
                s16x4 pk;
#pragma unroll
                for (int r = 0; r < 4; ++r) pk[r] = (short)f2bf(acc[mi][ni][r] + bv);
                const int t0 = gm0 & 2047;
                const int j = gn & 63;
                const int tsw = (t0 & ~63) | ((((t0 >> 3) & 7) ^ (j & 7)) << 3) | (t0 & 7);
                *(s16x4*)&outb[(((size_t)((gm0 >> 11) * 16 + (gn >> 6))) * 64 + j) * 2048 +
                               tsw] = pk;
            }
        }
    }
}

// ---------------------------------------------------------------------------
// Flash attention, 32x32x16 MFMA, in-register softmax, s-split wave pairs.
// __launch_bounds__(512, 4): R9's (512,6) capped VGPRs below the ~50-reg
// live set -> accumulator spilled to scratch (229 MB writes). 4 waves/EU
// keeps VGPR cap at 128 -> no spill; 4 blocks/CU by LDS.
// ---------------------------------------------------------------------------
__global__ __launch_bounds__(512, 4) void attn_kernel(
    const short* __restrict__ Qp, const short* __restrict__ Kp,
    const short* __restrict__ VTp, short* __restrict__ heads) {
    __shared__ union SMem {
        struct {
            short Ks[2][4096];   // [parity][64x64 tile], chunk-swizzled
            short VTs[2][4096];
        } t;
        float accF[8192];        // epilogue pair-combine scratch (32 KB)
    } sm;
    __shared__ float tsx[256];
    const int tid = threadIdx.x;
    const int w = tid >> 6, lane = tid & 63;
    const int l31 = lane & 31, hi = lane >> 5;
    const int g = w >> 1, par = w & 1;
    const int id = blockIdx.x;
    const int swz = (id & 7) * 128 + (id >> 3);  // 1024 blocks, XCD-contiguous
    const int qbase = (swz & 15) * 128;
    const int bh = swz >> 4;
    const size_t kvbase = (size_t)bh * TT * 64;

    // Q B-fragments: col q = l31, k(d) = sl*16 + hi*8 + j
    bf16x8 qf[4];
    {
        const short* Qw = Qp + kvbase + (size_t)(qbase + g * 32 + l31) * 64 + hi * 8;
#pragma unroll
        for (int sl = 0; sl < 4; ++sl) qf[sl] = *(const bf16x8*)(Qw + sl * 16);
    }

    f32x16 acc[2];
#pragma unroll
    for (int vb = 0; vb < 2; ++vb)
#pragma unroll
        for (int r = 0; r < 16; ++r) acc[vb][r] = 0.f;
    float ts_acc = 0.f;

    // staging: 4 gll16/thread covers 2 K-tiles + 2 V-tiles (even+odd parity)
    const int strow = w * 8 + (lane >> 3);
    const int sca = lane & 7;  // sources pre-swizzled in global -> linear copy

    for (int it = 0; it < 16; ++it) {
        const int s0 = it * 128;
        gll16(Kp + kvbase + (size_t)(s0 + strow) * 64 + sca * 8, &sm.t.Ks[0][w * 512]);
        gll16(Kp + kvbase + (size_t)(s0 + 64 + strow) * 64 + sca * 8,
              &sm.t.Ks[1][w * 512]);
        gll16(VTp + kvbase + (size_t)strow * 2048 + s0 + sca * 8, &sm.t.VTs[0][w * 512]);
        gll16(VTp + kvbase + (size_t)strow * 2048 + s0 + 64 + sca * 8,
              &sm.t.VTs[1][w * 512]);
        __syncthreads();

        u32x4 pa[4];  // PV A-frags
#pragma unroll
        for (int sb = 0; sb < 2; ++sb) {
            f32x16 e;
#pragma unroll
            for (int r = 0; r < 16; ++r) e[r] = 0.f;
            __builtin_amdgcn_s_setprio(1);
#pragma unroll
            for (int sl = 0; sl < 4; ++sl) {
                const int row = sb * 32 + l31;
                const bf16x8 kf = *(const bf16x8*)&sm.t.Ks[par][row * 64 +
                                                        (((sl * 2 + hi) ^ (row & 7)) * 8)];
                e = __builtin_amdgcn_mfma_f32_32x32x16_bf16(kf, qf[sl], e, 0, 0, 0);
            }
            __builtin_amdgcn_s_setprio(0);
            float p[16];
#pragma unroll
            for (int r = 0; r < 16; ++r) p[r] = exp2f(e[r]);
#pragma unroll
            for (int r = 0; r < 16; r += 4)
                ts_acc += ((p[r] + p[r + 1]) + (p[r + 2] + p[r + 3]));
            unsigned u[4][2];
#pragma unroll
            for (int A = 0; A < 4; ++A)
#pragma unroll
                for (int b = 0; b < 2; ++b)
                    asm("v_cvt_pk_bf16_f32 %0, %1, %2"
                        : "=v"(u[A][b])
                        : "v"(p[4 * A + 2 * b]), "v"(p[4 * A + 2 * b + 1]));
#pragma unroll
            for (int k1 = 0; k1 < 2; ++k1) {
#pragma unroll
                for (int b = 0; b < 2; ++b) {
                    unsigned p0 = u[2 * k1][b], p1 = u[2 * k1 + 1][b];
                    asm("v_permlane32_swap_b32 %0, %1" : "+v"(p0), "+v"(p1));
                    pa[sb * 2 + k1][b] = p0;
                    pa[sb * 2 + k1][2 + b] = p1;
                }
            }
        }
        __builtin_amdgcn_s_setprio(1);
#pragma unroll
        for (int vb = 0; vb < 2; ++vb) {
#pragma unroll
            for (int ks = 0; ks < 4; ++ks) {
                const int row = vb * 32 + l31;
                const bf16x8 vf = *(const bf16x8*)&sm.t.VTs[par][row * 64 +
                                                        (((ks * 2 + hi) ^ (row & 7)) * 8)];
                const bf16x8 paf = __builtin_bit_cast(bf16x8, pa[ks]);
                acc[vb] = __builtin_amdgcn_mfma_f32_32x32x16_bf16(paf, vf, acc[vb],
                                                                  0, 0, 0);
            }
        }
        __builtin_amdgcn_s_setprio(0);
        __syncthreads();
    }

    // pair-combine: odd-parity wave dumps partials to LDS; even adds them
    if (par == 1) {
#pragma unroll
        for (int vb = 0; vb < 2; ++vb)
#pragma unroll
            for (int r = 0; r < 16; ++r)
                sm.accF[g * 2048 + (vb * 16 + r) * 64 + lane] = acc[vb][r];
        tsx[g * 64 + lane] = ts_acc;
    }
    __syncthreads();
    if (par == 0) {
#pragma unroll
        for (int vb = 0; vb < 2; ++vb)
#pragma unroll
            for (int r = 0; r < 16; ++r)
                acc[vb][r] += sm.accF[g * 2048 + (vb * 16 + r) * 64 + lane];
        ts_acc += tsx[g * 64 + lane];

        float l = ts_acc;
        l += __shfl_xor(l, 32);
        const float linv = 1.0f / l;
        const int b_ = bh >> 4, h = bh & 15;
#pragma unroll
        for (int r = 0; r < 16; ++r) {
            const int qrow = (r & 3) + 8 * (r >> 2) + 4 * hi;
            const float inv = __shfl(linv, qrow);
            const int qg = qbase + g * 32 + qrow;
            const size_t base = ((size_t)(b_ * TT + qg)) * 1024 + h * 64 + l31;
            heads[base] = (short)f2bf(acc[0][r] * inv);
            heads[base + 32] = (short)f2bf(acc[1][r] * inv);
        }
    }
}

extern "C" void kernel_launch(void* const* d_in, const int* in_sizes, int n_in,
                              void* d_out, int out_size, void* d_ws, size_t ws_size,
                              hipStream_t stream) {
    const float* q = (const float*)d_in[0];
    const float* k = (const float*)d_in[1];
    const float* v = (const float*)d_in[2];
    const float* Wq = (const float*)d_in[3];
    const float* bq = (const float*)d_in[4];
    const float* Wk = (const float*)d_in[5];
    const float* bk = (const float*)d_in[6];
    const float* Wv = (const float*)d_in[7];
    const float* bv = (const float*)d_in[8];
    const float* Wo = (const float*)d_in[9];
    const float* bo = (const float*)d_in[10];
    float* out = (float*)d_out;

    const size_t SEG = (size_t)4 * 16 * 2048 * 64;  // 8,388,608 bf16 elems
    short* Qp = (short*)d_out;  // d_out doubles as Q/K scratch until final GEMM
    short* Kp = Qp + SEG;
    // ws: Xq | Xk (reused v->VT-input) | Wt x4 | VTp  (= 58.8 MB)
    short* ws = (short*)d_ws;
    short* Xq = ws;                  // later reused for heads
    short* Xk = Xq + SEG;
    short* Wt = Xk + SEG;
    short* VTp = Wt + (size_t)4 * 1024 * 1024;

    dim3 blk(256);
    const int n8 = (int)(SEG / 8);
    dim3 gcv2((n8 + 255) / 256, 2);
    dim3 gcv((n8 + 255) / 256);
    dim3 gwa(16, 16, 4);
    const size_t WSEG = (size_t)1024 * 1024;

    conv_w_all<<<gwa, blk, 0, stream>>>(Wq, Wk, Wv, Wo, Wt);
    conv_x2_kernel<<<gcv2, blk, 0, stream>>>(q, Xq, k, Xk, n8);
    gemm_qk_kernel<<<dim3(512, 1, 2), blk, 0, stream>>>(Xq, Xk, Wt, bq, bk, Qp, Kp);
    conv_x2_kernel<<<gcv, blk, 0, stream>>>(v, Xk, v, Xk, n8);  // v -> Xk (reuse)
    gemm_kernel<1><<<dim3(512), blk, 0, stream>>>(Xk, Wt + 2 * WSEG, bv, VTp, nullptr);
    attn_kernel<<<dim3(1024), dim3(512), 0, stream>>>(Qp, Kp, VTp, Xq /*heads*/);
    gemm_kernel<2><<<dim3(512), blk, 0, stream>>>(Xq, Wt + 3 * WSEG, bo, nullptr, out);
}

// Round 11
// 224.956 us; speedup vs baseline: 1.4739x; 1.1763x over previous
//
#include <hip/hip_runtime.h>
#include <hip/hip_bf16.h>

// B=4, T=2048, D=1024, H=16, DK=DV=64
#define TT 2048

typedef __attribute__((ext_vector_type(8))) short bf16x8;
typedef __attribute__((ext_vector_type(4))) short s16x4;
typedef __attribute__((ext_vector_type(4))) float f32x4;
typedef __attribute__((ext_vector_type(16))) float f32x16;
typedef __attribute__((ext_vector_type(4))) unsigned int u32x4;

__device__ __forceinline__ unsigned short f2bf(float x) {
    unsigned u = __float_as_uint(x);
    return (unsigned short)((u + 0x7fffu + ((u >> 16) & 1u)) >> 16);
}

typedef __attribute__((address_space(1))) const unsigned int g_u32;
typedef __attribute__((address_space(3))) unsigned int l_u32;
__device__ __forceinline__ void gll16(const void* g, void* l) {
    __builtin_amdgcn_global_load_lds((g_u32*)g, (l_u32*)l, 16, 0, 0);
}

// scale/sqrt(dk) * log2(e), folded into Q so attention P = exp2(e) directly
#define QSCALE 0.1803368801111244f

// ---------------------------------------------------------------------------
// fp32 -> bf16 convert, all three activations in one launch (grid.y = 0..2)
// ---------------------------------------------------------------------------
__global__ __launch_bounds__(256) void conv_x3_kernel(
    const float* __restrict__ s0, short* __restrict__ d0,
    const float* __restrict__ s1, short* __restrict__ d1,
    const float* __restrict__ s2, short* __restrict__ d2, int n8) {
    const int i = blockIdx.x * 256 + threadIdx.x;
    if (i >= n8) return;
    const float* src = (blockIdx.y == 0) ? s0 : (blockIdx.y == 1) ? s1 : s2;
    short* dst = (blockIdx.y == 0) ? d0 : (blockIdx.y == 1) ? d1 : d2;
    const float4 a = ((const float4*)src)[2 * i];
    const float4 b = ((const float4*)src)[2 * i + 1];
    bf16x8 o;
    o[0] = (short)f2bf(a.x); o[1] = (short)f2bf(a.y);
    o[2] = (short)f2bf(a.z); o[3] = (short)f2bf(a.w);
    o[4] = (short)f2bf(b.x); o[5] = (short)f2bf(b.y);
    o[6] = (short)f2bf(b.z); o[7] = (short)f2bf(b.w);
    ((bf16x8*)dst)[i] = o;
}

// ---------------------------------------------------------------------------
// Weight transpose+convert, all four weights in one launch (grid.z = 0..3)
// ---------------------------------------------------------------------------
__global__ __launch_bounds__(256) void conv_w_all(
    const float* __restrict__ W0, const float* __restrict__ W1,
    const float* __restrict__ W2, const float* __restrict__ W3,
    short* __restrict__ Wt) {
    __shared__ short t[64][72];
    const int z = blockIdx.z;
    const float* W = (z == 0) ? W0 : (z == 1) ? W1 : (z == 2) ? W2 : W3;
    short* dst = Wt + (size_t)z * 1024 * 1024;
    const int bx = blockIdx.x;
    const int by = blockIdx.y;
    const int tid = threadIdx.x;
    const int d0 = by * 64;
    {
        const int r = tid >> 2;
        const int c0 = (tid & 3) * 16;
        const float* srow = (z < 3)
                                ? (W + (size_t)bx * 65536 + (size_t)(d0 + r) * 64 + c0)
                                : (W + (size_t)(d0 + r) * 1024 + bx * 64 + c0);
#pragma unroll
        for (int q = 0; q < 4; ++q) {
            const float4 v = *(const float4*)(srow + q * 4);
            t[r][c0 + q * 4 + 0] = (short)f2bf(v.x);
            t[r][c0 + q * 4 + 1] = (short)f2bf(v.y);
            t[r][c0 + q * 4 + 2] = (short)f2bf(v.z);
            t[r][c0 + q * 4 + 3] = (short)f2bf(v.w);
        }
    }
    __syncthreads();
    {
        const int j = tid >> 2;
        const int c0 = (tid & 3) * 16;
        bf16x8 v0, v1;
#pragma unroll
        for (int q = 0; q < 8; ++q) v0[q] = t[c0 + q][j];
#pragma unroll
        for (int q = 0; q < 8; ++q) v1[q] = t[c0 + 8 + q][j];
        short* drow = dst + (size_t)(bx * 64 + j) * 1024 + d0 + c0;
        *(bf16x8*)drow = v0;
        *(bf16x8*)(drow + 8) = v1;
    }
}

// ---------------------------------------------------------------------------
// Shared GEMM main loop (128x128x64, 4 waves): computes acc for tile (m0,n0).
// ---------------------------------------------------------------------------
__device__ __forceinline__ void gemm_core(const short* __restrict__ A,
                                          const short* __restrict__ Bt,
                                          int m0, int n0, int tid,
                                          short* As, short* Bs, f32x4 acc[4][4]) {
    const int w = tid >> 6, lane = tid & 63;
    const int l16 = lane & 15, lk = lane >> 4;
    const int wr = w >> 1, wc = w & 1;
    const int srow = lane >> 3;
    const int schk = lane & 7;
#pragma unroll
    for (int i = 0; i < 4; ++i)
#pragma unroll
        for (int j = 0; j < 4; ++j)
#pragma unroll
            for (int r = 0; r < 4; ++r) acc[i][j][r] = 0.f;

    for (int k0 = 0; k0 < 1024; k0 += 64) {
#pragma unroll
        for (int p = 0; p < 4; ++p) {
            const int row = p * 32 + w * 8 + srow;
            const int ca = schk ^ (row & 7);
            gll16(A + (size_t)(m0 + row) * 1024 + k0 + ca * 8, &As[p * 2048 + w * 512]);
            gll16(Bt + (size_t)(n0 + row) * 1024 + k0 + ca * 8, &Bs[p * 2048 + w * 512]);
        }
        __syncthreads();
#pragma unroll
        for (int kc = 0; kc < 2; ++kc) {
            bf16x8 a[4], b[4];
#pragma unroll
            for (int mi = 0; mi < 4; ++mi) {
                const int row = wr * 64 + mi * 16 + l16;
                a[mi] = *(const bf16x8*)&As[row * 64 + (((kc * 4 + lk) ^ (row & 7)) * 8)];
            }
#pragma unroll
            for (int ni = 0; ni < 4; ++ni) {
                const int row = wc * 64 + ni * 16 + l16;
                b[ni] = *(const bf16x8*)&Bs[row * 64 + (((kc * 4 + lk) ^ (row & 7)) * 8)];
            }
#pragma unroll
            for (int mi = 0; mi < 4; ++mi)
#pragma unroll
                for (int ni = 0; ni < 4; ++ni)
                    acc[mi][ni] = __builtin_amdgcn_mfma_f32_16x16x32_bf16(
                        a[mi], b[ni], acc[mi][ni], 0, 0, 0);
        }
        __syncthreads();
    }
}

// ---------------------------------------------------------------------------
// Q and K projections fused in one launch (grid.z = 0:Q, 1:K)
// ---------------------------------------------------------------------------
__global__ __launch_bounds__(256) void gemm_qk_kernel(
    const short* __restrict__ Xq, const short* __restrict__ Xk,
    const short* __restrict__ Wt, const float* __restrict__ bq,
    const float* __restrict__ bk, short* __restrict__ Qp,
    short* __restrict__ Kp) {
    __shared__ short As[8192];
    __shared__ short Bs[8192];
    const int z = blockIdx.z;
    const short* A = z ? Xk : Xq;
    const short* Bt = Wt + (size_t)z * 1024 * 1024;
    const float* bias = z ? bk : bq;
    short* outb = z ? Kp : Qp;
    const int id = blockIdx.x;
    const int swz = (id & 7) * 64 + (id >> 3);
    const int n0 = (swz & 7) * 128;
    const int m0 = (swz >> 3) * 128;
    const int tid = threadIdx.x;
    const int w = tid >> 6, lane = tid & 63;
    const int l16 = lane & 15, lk = lane >> 4;
    const int wr = w >> 1, wc = w & 1;

    f32x4 acc[4][4];
    gemm_core(A, Bt, m0, n0, tid, As, Bs, acc);

#pragma unroll
    for (int mi = 0; mi < 4; ++mi) {
        const int gm0 = m0 + wr * 64 + mi * 16 + lk * 4;
#pragma unroll
        for (int ni = 0; ni < 4; ++ni) {
            const int gn = n0 + wc * 64 + ni * 16 + l16;
            const float bv = bias[gn];
            if (z == 0) {
                const float bvs = bv * QSCALE;
#pragma unroll
                for (int r = 0; r < 4; ++r) {
                    const int gm = gm0 + r;
                    outb[((size_t)((gm >> 11) * 16 + (gn >> 6)) * 2048 + (gm & 2047)) * 64 +
                         (gn & 63)] = (short)f2bf(fmaf(acc[mi][ni][r], QSCALE, bvs));
                }
            } else {
#pragma unroll
                for (int r = 0; r < 4; ++r) {
                    const int gm = gm0 + r;
                    const int t = gm & 2047;
                    const int j = gn & 63;
                    const int jsw = (((j >> 3) ^ (t & 7)) << 3) | (j & 7);
                    outb[((size_t)((gm >> 11) * 16 + (gn >> 6)) * 2048 + t) * 64 + jsw] =
                        (short)f2bf(acc[mi][ni][r] + bv);
                }
            }
        }
    }
}

// ---------------------------------------------------------------------------
// MODE 1: V^T bf16 out [b,h,j,t] chunk-swizzled t^(j&7);  MODE 2: fp32 final
// ---------------------------------------------------------------------------
template <int MODE>
__global__ __launch_bounds__(256) void gemm_kernel(
    const short* __restrict__ A, const short* __restrict__ Bt,
    const float* __restrict__ bias, short* __restrict__ outb,
    float* __restrict__ outf) {
    __shared__ short As[8192];
    __shared__ short Bs[8192];
    const int id = blockIdx.x;
    const int swz = (id & 7) * 64 + (id >> 3);
    const int n0 = (swz & 7) * 128;
    const int m0 = (swz >> 3) * 128;
    const int tid = threadIdx.x;
    const int w = tid >> 6, lane = tid & 63;
    const int l16 = lane & 15, lk = lane >> 4;
    const int wr = w >> 1, wc = w & 1;

    f32x4 acc[4][4];
    gemm_core(A, Bt, m0, n0, tid, As, Bs, acc);

#pragma unroll
    for (int mi = 0; mi < 4; ++mi) {
        const int gm0 = m0 + wr * 64 + mi * 16 + lk * 4;
#pragma unroll
        for (int ni = 0; ni < 4; ++ni) {
            const int gn = n0 + wc * 64 + ni * 16 + l16;
            const float bv = bias[gn];
            if (MODE == 2) {
#pragma unroll
                for (int r = 0; r < 4; ++r)
                    outf[(size_t)(gm0 + r) * 1024 + gn] = acc[mi][ni][r] + bv;
            } else {  // MODE 1
                s16x4 pk;
#pragma unroll
                for (int r = 0; r < 4; ++r) pk[r] = (short)f2bf(acc[mi][ni][r] + bv);
                const int t0 = gm0 & 2047;
                const int j = gn & 63;
                const int tsw = (t0 & ~63) | ((((t0 >> 3) & 7) ^ (j & 7)) << 3) | (t0 & 7);
                *(s16x4*)&outb[(((size_t)((gm0 >> 11) * 16 + (gn >> 6))) * 64 + j) * 2048 +
                               tsw] = pk;
            }
        }
    }
}

// ---------------------------------------------------------------------------
// Flash attention — the proven R7 kernel (115.6 us): 32x32x16 MFMA, QBLK=32
// per wave, fully in-register softmax via cvt_pk + permlane32_swap, swapped
// QK^T, no-max softmax (Q pre-scaled), double-buffered prefetch staging.
// 512 blocks x 8 waves; each wave owns the full s-range for its 32 q-rows.
// ---------------------------------------------------------------------------
__global__ __launch_bounds__(512, 4) void attn_kernel(
    const short* __restrict__ Qp, const short* __restrict__ Kp,
    const short* __restrict__ VTp, short* __restrict__ heads) {
    __shared__ short Ks[2][4096];   // [64][64] chunk-swizzled, double-buffered
    __shared__ short VTs[2][4096];
    const int tid = threadIdx.x;
    const int w = tid >> 6, lane = tid & 63;
    const int l31 = lane & 31, hi = lane >> 5;
    const int id = blockIdx.x;
    const int swz = (id & 7) * 64 + (id >> 3);  // 512 blocks, XCD-contiguous
    const int qbase = (swz & 7) * 256;          // 8 blocks per bh
    const int bh = swz >> 3;
    const size_t kvbase = (size_t)bh * TT * 64;

    // Q B-fragments: col q = l31, k(d) = sl*16 + hi*8 + j
    bf16x8 qf[4];
    {
        const short* Qw = Qp + kvbase + (size_t)(qbase + w * 32 + l31) * 64 + hi * 8;
#pragma unroll
        for (int sl = 0; sl < 4; ++sl) qf[sl] = *(const bf16x8*)(Qw + sl * 16);
    }

    f32x16 acc[2];
#pragma unroll
    for (int vb = 0; vb < 2; ++vb)
#pragma unroll
        for (int r = 0; r < 16; ++r) acc[vb][r] = 0.f;
    float ts_acc = 0.f;  // per-lane partial of sum_s P[q=l31][s]

    // staging: 1 K + 1 V gll16 per thread (512 thr cover 64x64 tile each)
    const int strow = w * 8 + (lane >> 3);
    const int sca = lane & 7;  // source pre-swizzled -> linear copy
    auto STAGE = [&](int s0, int nb) {
        gll16(Kp + kvbase + (size_t)(s0 + strow) * 64 + sca * 8, &Ks[nb][w * 512]);
        gll16(VTp + kvbase + (size_t)strow * 2048 + s0 + sca * 8, &VTs[nb][w * 512]);
    };

    STAGE(0, 0);
    __syncthreads();
    int nb = 0;

    for (int s0 = 0; s0 < TT; s0 += 64) {
        if (s0 + 64 < TT) STAGE(s0 + 64, nb ^ 1);  // prefetch next tile

        u32x4 pa[4];  // PV A-frags: pa[ks][c], k = s = ks*16 + hi*8 + 2c..
#pragma unroll
        for (int sb = 0; sb < 2; ++sb) {
            f32x16 e;
#pragma unroll
            for (int r = 0; r < 16; ++r) e[r] = 0.f;
            __builtin_amdgcn_s_setprio(1);
#pragma unroll
            for (int sl = 0; sl < 4; ++sl) {
                const int row = sb * 32 + l31;
                const bf16x8 kf = *(const bf16x8*)&Ks[nb][row * 64 +
                                                          (((sl * 2 + hi) ^ (row & 7)) * 8)];
                e = __builtin_amdgcn_mfma_f32_32x32x16_bf16(kf, qf[sl], e, 0, 0, 0);
            }
            __builtin_amdgcn_s_setprio(0);
            // p = exp2(e); rows held: s = (reg&3) + 8*(reg>>2) + 4*hi (+32*sb)
            float p[16];
#pragma unroll
            for (int r = 0; r < 16; ++r) p[r] = exp2f(e[r]);
#pragma unroll
            for (int r = 0; r < 16; r += 4)
                ts_acc += ((p[r] + p[r + 1]) + (p[r + 2] + p[r + 3]));
            // u[A][b] = cvt_pk(p[4A+2b], p[4A+2b+1]) -> s-pair 8A + 4hi + 2b
            unsigned u[4][2];
#pragma unroll
            for (int A = 0; A < 4; ++A)
#pragma unroll
                for (int b = 0; b < 2; ++b)
                    asm("v_cvt_pk_bf16_f32 %0, %1, %2"
                        : "=v"(u[A][b])
                        : "v"(p[4 * A + 2 * b]), "v"(p[4 * A + 2 * b + 1]));
            // permlane32_swap assembles both wave-halves' A-fragments
#pragma unroll
            for (int k1 = 0; k1 < 2; ++k1) {
#pragma unroll
                for (int b = 0; b < 2; ++b) {
                    unsigned p0 = u[2 * k1][b], p1 = u[2 * k1 + 1][b];
                    asm("v_permlane32_swap_b32 %0, %1" : "+v"(p0), "+v"(p1));
                    pa[sb * 2 + k1][b] = p0;
                    pa[sb * 2 + k1][2 + b] = p1;
                }
            }
        }
        // PV: A = P (row q = l31, k = s), B = V^T tile (col v = l31)
        __builtin_amdgcn_s_setprio(1);
#pragma unroll
        for (int vb = 0; vb < 2; ++vb) {
#pragma unroll
            for (int ks = 0; ks < 4; ++ks) {
                const int row = vb * 32 + l31;
                const bf16x8 vf = *(const bf16x8*)&VTs[nb][row * 64 +
                                                           (((ks * 2 + hi) ^ (row & 7)) * 8)];
                const bf16x8 paf = __builtin_bit_cast(bf16x8, pa[ks]);
                acc[vb] = __builtin_amdgcn_mfma_f32_32x32x16_bf16(paf, vf, acc[vb],
                                                                  0, 0, 0);
            }
        }
        __builtin_amdgcn_s_setprio(0);
        __syncthreads();
        nb ^= 1;
    }
    // l per q: combine wave halves (lane q and q+32 hold the two halves)
    float l = ts_acc;
    l += __shfl_xor(l, 32);
    const float linv = 1.0f / l;
    const int b_ = bh >> 4, h = bh & 15;
#pragma unroll
    for (int r = 0; r < 16; ++r) {
        const int qrow = (r & 3) + 8 * (r >> 2) + 4 * hi;
        const float inv = __shfl(linv, qrow);
        const int qg = qbase + w * 32 + qrow;
        const size_t base = ((size_t)(b_ * TT + qg)) * 1024 + h * 64 + l31;
        heads[base] = (short)f2bf(acc[0][r] * inv);
        heads[base + 32] = (short)f2bf(acc[1][r] * inv);
    }
}

extern "C" void kernel_launch(void* const* d_in, const int* in_sizes, int n_in,
                              void* d_out, int out_size, void* d_ws, size_t ws_size,
                              hipStream_t stream) {
    const float* q = (const float*)d_in[0];
    const float* k = (const float*)d_in[1];
    const float* v = (const float*)d_in[2];
    const float* Wq = (const float*)d_in[3];
    const float* bq = (const float*)d_in[4];
    const float* Wk = (const float*)d_in[5];
    const float* bk = (const float*)d_in[6];
    const float* Wv = (const float*)d_in[7];
    const float* bv = (const float*)d_in[8];
    const float* Wo = (const float*)d_in[9];
    const float* bo = (const float*)d_in[10];
    float* out = (float*)d_out;

    const size_t SEG = (size_t)4 * 16 * 2048 * 64;  // 8,388,608 bf16 elems
    // d_out (33.5 MB): Xv scratch during converts/V-GEMM, then Qp|Kp.
    short* Qp = (short*)d_out;
    short* Kp = Qp + SEG;
    short* Xv = (short*)d_out;  // consumed by V-GEMM before gemm_qk overwrites
    // ws: Xq | Xk | Wt x4 | VTp  (= 41.6 MB)
    short* ws = (short*)d_ws;
    short* Xq = ws;  // later reused for heads
    short* Xk = Xq + SEG;
    short* Wt = Xk + SEG;
    short* VTp = Wt + (size_t)4 * 1024 * 1024;

    dim3 blk(256);
    const int n8 = (int)(SEG / 8);
    dim3 gcv3((n8 + 255) / 256, 3);
    dim3 gwa(16, 16, 4);
    const size_t WSEG = (size_t)1024 * 1024;

    conv_w_all<<<gwa, blk, 0, stream>>>(Wq, Wk, Wv, Wo, Wt);
    conv_x3_kernel<<<gcv3, blk, 0, stream>>>(q, Xq, k, Xk, v, Xv, n8);
    gemm_kernel<1><<<dim3(512), blk, 0, stream>>>(Xv, Wt + 2 * WSEG, bv, VTp, nullptr);
    gemm_qk_kernel<<<dim3(512, 1, 2), blk, 0, stream>>>(Xq, Xk, Wt, bq, bk, Qp, Kp);
    attn_kernel<<<dim3(512), dim3(512), 0, stream>>>(Qp, Kp, VTp, Xq /*heads*/);
    gemm_kernel<2><<<dim3(512), blk, 0, stream>>>(Xq, Wt + 3 * WSEG, bo, nullptr, out);
}